// Round 11
// baseline (342.487 us; speedup 1.0000x reference)
//
#include <hip/hip_runtime.h>
#include <hip/hip_bf16.h>

// TransformerLayer: B=2, T=2048, C=768, H=12, D=64, FF=3072. fp32 I/O.
// Round 11: attention K/V staging via global_load_lds into split-plane
// [2][64][32] LDS layouts (manual b128 staging writes were 8-way bank
// conflicted -> 5.6e6 conflict cycles; GLDS is sequential-bank + no VGPR
// round-trip; 64B rows keep fragment reads 2-way). All else = round 10.
//
// Workspace layout (bytes):
//   0         QKVqk bf16 4096x1536 (q|k)      }
//   12582912  VT    bf16 768x4096 (V^T)       } Fb (bf16 4096x3072) aliases
//   18874368  Ob    bf16 4096x768             } [0, 25165824)
//   25165824  X2   fp32 4096x768
//   37748736  Hb   bf16 4096x768 (LN1/LN2 out)
//   44040192  Wqkv bf16 2304x768
//   47579136  Wob  bf16 768x768
//   48758784  W1b  bf16 3072x768
//   53477376  W2b  bf16 768x3072
//   58195968  bqkv fp32 2304
//   58205184  bias_rel fp32 12x4095 (pre-scaled by 1/ln2)
//   58401744  qpart fp32 2x16x64
//   58409936  gate fp32 24

#define Tn 2048
#define Cn 768
#define Hn 12
#define Dn 64
#define FFn 3072
#define Mn 4096
#define QKVS 2304
#define LQK 1536

typedef __attribute__((ext_vector_type(8))) short bfrag;       // 8 bf16 (4 VGPR)
typedef __attribute__((ext_vector_type(8))) unsigned short us8;
typedef __attribute__((ext_vector_type(4))) float f32x4;

#define GLDS(gptr, lptr) __builtin_amdgcn_global_load_lds( \
    (const __attribute__((address_space(1))) void*)(gptr), \
    (__attribute__((address_space(3))) void*)(lptr), 16, 0, 0)

__device__ __forceinline__ unsigned short f2bu(float f){
  __hip_bfloat16 h = __float2bfloat16(f);
  return *(unsigned short*)&h;
}
__device__ __forceinline__ float bu2f(unsigned short u){
  union { unsigned int i; float f; } v; v.i = ((unsigned int)u) << 16; return v.f;
}
__device__ __forceinline__ us8 pack8(float4 a, float4 b){
  us8 c;
  c[0]=f2bu(a.x); c[1]=f2bu(a.y); c[2]=f2bu(a.z); c[3]=f2bu(a.w);
  c[4]=f2bu(b.x); c[5]=f2bu(b.y); c[6]=f2bu(b.z); c[7]=f2bu(b.w);
  return c;
}
__device__ __forceinline__ float fexp2(float x){ return __builtin_amdgcn_exp2f(x); }

__device__ __forceinline__ float block_reduce_sum(float v, float* sred){
  #pragma unroll
  for (int off = 32; off > 0; off >>= 1) v += __shfl_down(v, off, 64);
  __syncthreads();
  if ((threadIdx.x & 63) == 0) sred[threadIdx.x >> 6] = v;
  __syncthreads();
  return sred[0] + sred[1] + sred[2] + sred[3];
}

// ---- fused weight casts + bias_rel table + bias concat ----
// blocks: weights [0,3456) ; bias_rel [3456,3472) ; bqkv [3472,3481)
__global__ __launch_bounds__(256) void cast_all_kernel(
    const float* __restrict__ wq, const float* __restrict__ wk,
    const float* __restrict__ wv, const float* __restrict__ wo,
    const float* __restrict__ w1, const float* __restrict__ w2,
    const float* __restrict__ bq, const float* __restrict__ bk,
    const float* __restrict__ bv, const float* __restrict__ rel_embed,
    unsigned short* __restrict__ Wqkv, unsigned short* __restrict__ Wob,
    unsigned short* __restrict__ W1b, unsigned short* __restrict__ W2b,
    float* __restrict__ bias_rel, float* __restrict__ bqkv)
{
  const int blk = blockIdx.x;
  if (blk >= 3472){
    const int i = (blk - 3472) * 256 + threadIdx.x;   // 0..2303 exactly
    bqkv[i] = (i < Cn) ? bq[i] : (i < 2 * Cn) ? bk[i - Cn] : bv[i - 2 * Cn];
    return;
  }
  if (blk >= 3456){
    const int idx = (blk - 3456) * 256 + threadIdx.x;
    if (idx >= 4095) return;
    const int rel = idx - 2047;
    const int ab = rel < 0 ? -rel : rel;
    int bucket;
    if (ab < 80){
      bucket = ab;
    } else {
      const float lr = logf((float)ab * (1.0f / 80.0f)) * (1.0f / 2.3025851f);
      int lp = 80 + (int)(lr * 80.0f);
      bucket = lp < 159 ? lp : 159;
    }
    if (rel >= 0) bucket += 160;
    #pragma unroll
    for (int h = 0; h < Hn; h++)
      bias_rel[h * 4095 + idx] = rel_embed[bucket * Hn + h] * 1.44269504089f;
    return;
  }
  const float* src; unsigned short* dst; int i;
  if (blk < 288)      { src = wq; dst = Wqkv;               i = blk * 256 + threadIdx.x; }
  else if (blk < 576) { src = wk; dst = Wqkv + Cn * Cn;     i = (blk - 288) * 256 + threadIdx.x; }
  else if (blk < 864) { src = wv; dst = Wqkv + 2 * Cn * Cn; i = (blk - 576) * 256 + threadIdx.x; }
  else if (blk < 1152){ src = wo; dst = Wob;                i = (blk - 864) * 256 + threadIdx.x; }
  else if (blk < 2304){ src = w1; dst = W1b;                i = (blk - 1152) * 256 + threadIdx.x; }
  else                { src = w2; dst = W2b;                i = (blk - 2304) * 256 + threadIdx.x; }
  const float4 a = ((const float4*)src)[i * 2];
  const float4 b = ((const float4*)src)[i * 2 + 1];
  *(us8*)&dst[i * 8] = pack8(a, b);
}

// ---- LayerNorm: fp32 in -> bf16 out ----
__global__ __launch_bounds__(256) void ln_kernel(const float* __restrict__ xin,
    const float* __restrict__ w, const float* __restrict__ bsh,
    unsigned short* __restrict__ out)
{
  __shared__ float xs[Cn];
  __shared__ float sred[4];
  const size_t base = (size_t)blockIdx.x * Cn;
  float s = 0.f;
  for (int c = threadIdx.x; c < Cn; c += 256){
    float v = xin[base + c];
    xs[c] = v; s += v;
  }
  const float mean = block_reduce_sum(s, sred) * (1.f / Cn);
  float s2 = 0.f;
  for (int c = threadIdx.x; c < Cn; c += 256){
    float d = xs[c] - mean; s2 += d * d;
  }
  const float var = block_reduce_sum(s2, sred) * (1.f / Cn);
  const float rstd = rsqrtf(var + 1e-5f);
  for (int c = threadIdx.x; c < Cn; c += 256)
    out[base + c] = f2bu((xs[c] - mean) * rstd * w[c] + bsh[c]);
}

// ---- MFMA GEMM 128x128, single-buffered, XCD-swizzled 1-D grid ----
// id%8 = XCD; each XCD owns 4 consecutive bm-blocks (M=4096 fixed, 32 blocks).
// EPI 0: bf16 out (ldo stride); EPI 2: bf16 out = gelu_exact.
// TRANSV: blocks with bn>=1536 store transposed to vt[col-1536][row] (V^T).
template<int EPI, bool TRANSV>
__global__ __launch_bounds__(256) void gemm_mfma_kernel(
    const unsigned short* __restrict__ A, const unsigned short* __restrict__ Bw,
    const float* __restrict__ bias, unsigned short* __restrict__ vt,
    void* __restrict__ Cout, int M, int N, int K, int ldo)
{
  __shared__ __align__(16) unsigned short As[128 * 32];
  __shared__ __align__(16) unsigned short Bs[128 * 32];
  const int tid = threadIdx.x;
  const int lane = tid & 63, w = tid >> 6;
  const int nl = lane & 15, quad = lane >> 4;
  const int wm = w >> 1, wn = w & 1;
  const int id = blockIdx.x;
  const int bm = ((id & 7) * 4 + ((id >> 3) & 3)) * 128;   // XCD-local bm slice
  const int bn = (id >> 5) * 128;
  const int l4 = lane >> 2, lk = (lane & 3) * 8;

  f32x4 acc[4][4];
  #pragma unroll
  for (int i = 0; i < 4; i++)
    #pragma unroll
    for (int j = 0; j < 4; j++) acc[i][j] = (f32x4){0.f, 0.f, 0.f, 0.f};

  const int c0 = w, c1 = w + 4;
  const unsigned short* A0 = A + (size_t)(bm + c0 * 16 + l4) * K + lk;
  const unsigned short* A1 = A + (size_t)(bm + c1 * 16 + l4) * K + lk;
  const unsigned short* B0 = Bw + (size_t)(bn + c0 * 16 + l4) * K + lk;
  const unsigned short* B1 = Bw + (size_t)(bn + c1 * 16 + l4) * K + lk;

  for (int k0 = 0; k0 < K; k0 += 32){
    __syncthreads();
    GLDS(A0 + k0, &As[c0 * 512]); GLDS(A1 + k0, &As[c1 * 512]);
    GLDS(B0 + k0, &Bs[c0 * 512]); GLDS(B1 + k0, &Bs[c1 * 512]);
    __syncthreads();
    bfrag Af[4], Bf[4];
    #pragma unroll
    for (int mt = 0; mt < 4; mt++)
      Af[mt] = *(const bfrag*)&As[(wm * 64 + mt * 16 + nl) * 32 + quad * 8];
    #pragma unroll
    for (int nt = 0; nt < 4; nt++)
      Bf[nt] = *(const bfrag*)&Bs[(wn * 64 + nt * 16 + nl) * 32 + quad * 8];
    #pragma unroll
    for (int mt = 0; mt < 4; mt++)
      #pragma unroll
      for (int nt = 0; nt < 4; nt++)
        acc[mt][nt] = __builtin_amdgcn_mfma_f32_16x16x32_bf16(Af[mt], Bf[nt], acc[mt][nt], 0, 0, 0);
  }

  if (TRANSV && bn >= 1536){
    #pragma unroll
    for (int nt = 0; nt < 4; nt++){
      const int col = bn + wn * 64 + nt * 16 + nl;
      const float bv_ = bias[col];
      const int vcol = col - 1536;
      #pragma unroll
      for (int mt = 0; mt < 4; mt++){
        const int row0 = bm + wm * 64 + mt * 16 + quad * 4;
        unsigned short pk[4];
        #pragma unroll
        for (int r = 0; r < 4; r++) pk[r] = f2bu(acc[mt][nt][r] + bv_);
        *(uint2*)&vt[(size_t)vcol * Mn + row0] = *(uint2*)pk;
      }
    }
    return;
  }
  #pragma unroll
  for (int nt = 0; nt < 4; nt++){
    const int col = bn + wn * 64 + nt * 16 + nl;
    const float bv_ = bias[col];
    #pragma unroll
    for (int mt = 0; mt < 4; mt++){
      const int row0 = bm + wm * 64 + mt * 16 + quad * 4;
      #pragma unroll
      for (int r = 0; r < 4; r++){
        const size_t idx = (size_t)(row0 + r) * ldo + col;
        const float v = acc[mt][nt][r] + bv_;
        if (EPI == 2){
          ((unsigned short*)Cout)[idx] = f2bu(0.5f * v * (1.f + erff(v * 0.70710678118f)));
        } else {
          ((unsigned short*)Cout)[idx] = f2bu(v);
        }
      }
    }
  }
}

// ---- MFMA GEMM 64x64 tiles, XCD-swizzled 1-D grid; fp32 out = acc+bias+res ----
// id%8 = XCD; each XCD owns 8 consecutive bm-blocks (A-slice 3.1MB fits L2).
__global__ __launch_bounds__(256) void gemm_t64_kernel(
    const unsigned short* __restrict__ A, const unsigned short* __restrict__ Bw,
    const float* __restrict__ bias, const float* __restrict__ res,
    float* __restrict__ Cout, int M, int N, int K)
{
  __shared__ __align__(16) unsigned short As[64 * 32];
  __shared__ __align__(16) unsigned short Bs[64 * 32];
  const int tid = threadIdx.x;
  const int lane = tid & 63, w = tid >> 6;
  const int nl = lane & 15, quad = lane >> 4;
  const int id = blockIdx.x;
  const int bm = ((id & 7) * 8 + ((id >> 3) & 7)) * 64;    // XCD-local bm slice
  const int bn = (id >> 6) * 64;
  const int l4 = lane >> 2, lk = (lane & 3) * 8;

  f32x4 acc[4];
  #pragma unroll
  for (int j = 0; j < 4; j++) acc[j] = (f32x4){0.f, 0.f, 0.f, 0.f};

  const unsigned short* A0 = A + (size_t)(bm + w * 16 + l4) * K + lk;
  const unsigned short* B0 = Bw + (size_t)(bn + w * 16 + l4) * K + lk;

  for (int k0 = 0; k0 < K; k0 += 32){
    __syncthreads();
    GLDS(A0 + k0, &As[w * 512]);
    GLDS(B0 + k0, &Bs[w * 512]);
    __syncthreads();
    const bfrag Af = *(const bfrag*)&As[(w * 16 + nl) * 32 + quad * 8];
    bfrag Bf[4];
    #pragma unroll
    for (int nt = 0; nt < 4; nt++)
      Bf[nt] = *(const bfrag*)&Bs[(nt * 16 + nl) * 32 + quad * 8];
    #pragma unroll
    for (int nt = 0; nt < 4; nt++)
      acc[nt] = __builtin_amdgcn_mfma_f32_16x16x32_bf16(Af, Bf[nt], acc[nt], 0, 0, 0);
  }

  const int row0 = bm + w * 16 + quad * 4;
  #pragma unroll
  for (int nt = 0; nt < 4; nt++){
    const int col = bn + nt * 16 + nl;
    const float bv_ = bias[col];
    #pragma unroll
    for (int r = 0; r < 4; r++){
      const size_t idx = (size_t)(row0 + r) * N + col;
      Cout[idx] = acc[nt][r] + bv_ + res[idx];
    }
  }
}

// ---- qmean stage 1 (Q cols of QKVqk, stride 1536) ----
__global__ __launch_bounds__(256) void qmean_part_kernel(
    const unsigned short* __restrict__ QKVqk, float* __restrict__ qpart)
{
  __shared__ float ps[Cn];
  const int b = blockIdx.y, t0 = blockIdx.x * 128;
  const int tid = threadIdx.x;
  float a0 = 0.f, a1 = 0.f, a2 = 0.f;
  for (int r = 0; r < 128; r++){
    const size_t base = (size_t)(b * Tn + t0 + r) * LQK;
    a0 += bu2f(QKVqk[base + tid]);
    a1 += bu2f(QKVqk[base + tid + 256]);
    a2 += bu2f(QKVqk[base + tid + 512]);
  }
  ps[tid] = a0; ps[tid + 256] = a1; ps[tid + 512] = a2;
  __syncthreads();
  if (tid < Dn){
    float s = 0.f;
    #pragma unroll
    for (int hh = 0; hh < Hn; hh++) s += ps[hh * Dn + tid];
    qpart[(b * 16 + blockIdx.x) * Dn + tid] = s;
  }
}

// ---- gate[b,h] ----
__global__ __launch_bounds__(64) void gate_kernel(const float* __restrict__ qpart,
    const float* __restrict__ gur, const float* __restrict__ gi,
    const float* __restrict__ rsc, float* __restrict__ gate)
{
  const int b = blockIdx.x / Hn, h = blockIdx.x % Hn;
  const int d = threadIdx.x;
  float s = 0.f;
  #pragma unroll
  for (int blk = 0; blk < 16; blk++) s += qpart[(b * 16 + blk) * Dn + d];
  const float g = s * (1.f / (Hn * Tn));
  float vr = g * gur[h * Dn + d];
  float vu = g * gi[h * Dn + d];
  #pragma unroll
  for (int off = 32; off > 0; off >>= 1){
    vr += __shfl_down(vr, off, 64);
    vu += __shfl_down(vu, off, 64);
  }
  if (d == 0){
    const float gr = 1.f / (1.f + __expf(-vr));
    const float gu = 1.f / (1.f + __expf(-vu));
    gate[blockIdx.x] = 1.f + gu * rsc[h] * gr;
  }
}

// ---- MFMA flash attention; K/V staged via global_load_lds (split-plane) ----
// LDS: Qs 64x72 (dies -> bias_blk) | KsP [2][64][32] | VtP [2][64][32] |
//      Ptq 64x72 | lsh 4x64. Planes: 64B rows -> 2-way-or-less bank aliasing.
// GLDS lane map (per wave w, plane p): lane -> row w*16+(lane>>2),
// elem-offset p*32+(lane&3)*8; LDS dst = plane_base + w*512 elems + lane*16B.
__global__ __launch_bounds__(256) void attn_mfma_kernel(
    const unsigned short* __restrict__ QKVqk, const unsigned short* __restrict__ VT,
    const float* __restrict__ bias_rel, const float* __restrict__ gate,
    unsigned short* __restrict__ O)
{
  __shared__ __align__(16) char smem[35840];
  unsigned short* Qs = (unsigned short*)smem;            // 64x72, dies -> bias
  float* bias_blk    = (float*)smem;                     // 2111 floats
  unsigned short* KsP = (unsigned short*)(smem + 9216);  // [2][64][32]
  unsigned short* VtP = (unsigned short*)(smem + 17408); // [2][64][32]
  unsigned short* Ptq = (unsigned short*)(smem + 25600); // [query][key] 64x72
  float* lsh         = (float*)(smem + 34816);           // [wave][query] 4x64

  const int qbase = blockIdx.x * 64;
  const int h = blockIdx.y, b = blockIdx.z;
  const int tid = threadIdx.x;
  const float g = gate[b * Hn + h];
  const float* brow = bias_rel + h * 4095 + 1984 - qbase;
  const unsigned short* Q = QKVqk;
  const unsigned short* K = QKVqk + Cn;

  {
    const int row = tid >> 2, cg = (tid & 3) * 16;
    const us8* qp = (const us8*)(Q + (size_t)(b * Tn + qbase + row) * LQK + h * Dn + cg);
    *(us8*)&Qs[row * 72 + cg]     = qp[0];
    *(us8*)&Qs[row * 72 + cg + 8] = qp[1];
  }
  __syncthreads();

  const int lane = tid & 63, w = tid >> 6;
  const int nl = lane & 15, quad = lane >> 4;

  bfrag Qb[4][2];
  #pragma unroll
  for (int mt = 0; mt < 4; mt++){
    Qb[mt][0] = *(const bfrag*)&Qs[(mt * 16 + nl) * 72 + quad * 8];
    Qb[mt][1] = *(const bfrag*)&Qs[(mt * 16 + nl) * 72 + 32 + quad * 8];
  }
  __syncthreads();           // everyone done reading Qs
  for (int j = tid; j < 2111; j += 256) bias_blk[j] = brow[j] * g;

  const int wq = w & 1, wd = w >> 1;
  f32x4 Oa[2][2];            // [query-half a][dim-half d0]
  #pragma unroll
  for (int a = 0; a < 2; a++)
    #pragma unroll
    for (int d0 = 0; d0 < 2; d0++) Oa[a][d0] = (f32x4){0.f, 0.f, 0.f, 0.f};
  float l_part[4] = {0.f, 0.f, 0.f, 0.f};

  // GLDS staging pointers: wave w stages K-keys/V-dims [w*16, w*16+16)
  const int l2 = lane >> 2, l3 = lane & 3;
  const unsigned short* kg0 = K + (size_t)(b * Tn + w * 16 + l2) * LQK + h * Dn + l3 * 8;
  const unsigned short* vg0 = VT + (size_t)(h * Dn + w * 16 + l2) * Mn + (size_t)b * Tn + l3 * 8;
  unsigned short* ksw0 = KsP + w * 512;          // plane 0 dest
  unsigned short* ksw1 = KsP + 2048 + w * 512;   // plane 1 dest
  unsigned short* vtw0 = VtP + w * 512;
  unsigned short* vtw1 = VtP + 2048 + w * 512;

  for (int kt = 0; kt < 32; kt++){
    const int kbase = kt * 64;
    __syncthreads();                    // prior tile's reads done
    {
      const unsigned short* kg = kg0 + (size_t)kbase * LQK;
      GLDS(kg,      ksw0);              // dims 0..31
      GLDS(kg + 32, ksw1);              // dims 32..63
      const unsigned short* vg = vg0 + kbase;
      GLDS(vg,      vtw0);              // keys 0..31
      GLDS(vg + 32, vtw1);              // keys 32..63
    }
    __syncthreads();                    // drain GLDS

    // S^T: wave w owns key-subtile w. A = K frags (plane-split).
    const bfrag Ka0 = *(const bfrag*)&KsP[(w * 16 + nl) * 32 + quad * 8];
    const bfrag Ka1 = *(const bfrag*)&KsP[2048 + (w * 16 + nl) * 32 + quad * 8];
    const int bofs = kbase + w * 16 + quad * 4 + 63 - nl;
    #pragma unroll
    for (int mt = 0; mt < 4; mt++){
      f32x4 z = (f32x4){0.f, 0.f, 0.f, 0.f};
      z = __builtin_amdgcn_mfma_f32_16x16x32_bf16(Ka0, Qb[mt][0], z, 0, 0, 0);
      z = __builtin_amdgcn_mfma_f32_16x16x32_bf16(Ka1, Qb[mt][1], z, 0, 0, 0);
      unsigned short pk[4];
      #pragma unroll
      for (int r = 0; r < 4; r++){
        const float p = fexp2(z[r] * 0.18033688f + bias_blk[bofs - mt * 16 + r]);
        l_part[mt] += p;
        pk[r] = f2bu(p);
      }
      *(uint2*)&Ptq[(mt * 16 + nl) * 72 + w * 16 + quad * 4] = *(uint2*)pk;
    }
    __syncthreads();                    // P visible to all waves

    // O^T += V^T.P : wave (wq, wd): queries wq*32..+31, dims wd*32..+31
    bfrag Vf[2][2], Pf[2][2];
    #pragma unroll
    for (int d0 = 0; d0 < 2; d0++){
      const int dt = wd * 2 + d0;
      Vf[d0][0] = *(const bfrag*)&VtP[(dt * 16 + nl) * 32 + quad * 8];
      Vf[d0][1] = *(const bfrag*)&VtP[2048 + (dt * 16 + nl) * 32 + quad * 8];
    }
    #pragma unroll
    for (int a = 0; a < 2; a++){
      const int qt = wq * 2 + a;
      Pf[a][0] = *(const bfrag*)&Ptq[(qt * 16 + nl) * 72 + quad * 8];
      Pf[a][1] = *(const bfrag*)&Ptq[(qt * 16 + nl) * 72 + 32 + quad * 8];
    }
    #pragma unroll
    for (int a = 0; a < 2; a++)
      #pragma unroll
      for (int d0 = 0; d0 < 2; d0++){
        Oa[a][d0] = __builtin_amdgcn_mfma_f32_16x16x32_bf16(Vf[d0][0], Pf[a][0], Oa[a][d0], 0, 0, 0);
        Oa[a][d0] = __builtin_amdgcn_mfma_f32_16x16x32_bf16(Vf[d0][1], Pf[a][1], Oa[a][d0], 0, 0, 0);
      }
  }

  // ---- epilogue ----
  #pragma unroll
  for (int mt = 0; mt < 4; mt++){
    float l = l_part[mt];
    l += __shfl_xor(l, 16, 64);
    l += __shfl_xor(l, 32, 64);
    if (quad == 0) lsh[w * 64 + mt * 16 + nl] = l;
  }
  __syncthreads();
  #pragma unroll
  for (int a = 0; a < 2; a++){
    const int q = (wq * 2 + a) * 16 + nl;
    const float linv = 1.f / (lsh[q] + lsh[64 + q] + lsh[128 + q] + lsh[192 + q]);
    unsigned short* orow = O + (size_t)(b * Tn + qbase + q) * Cn + h * Dn;
    #pragma unroll
    for (int d0 = 0; d0 < 2; d0++){
      unsigned short pk[4];
      #pragma unroll
      for (int r = 0; r < 4; r++) pk[r] = f2bu(Oa[a][d0][r] * linv);
      *(uint2*)&orow[(wd * 2 + d0) * 16 + quad * 4] = *(uint2*)pk;
    }
  }
}

extern "C" void kernel_launch(void* const* d_in, const int* in_sizes, int n_in,
                              void* d_out, int out_size, void* d_ws, size_t ws_size,
                              hipStream_t stream)
{
  const float* x     = (const float*)d_in[0];
  const float* ln1_w = (const float*)d_in[1];
  const float* ln1_b = (const float*)d_in[2];
  const float* wq    = (const float*)d_in[3];
  const float* bq    = (const float*)d_in[4];
  const float* wk    = (const float*)d_in[5];
  const float* bk    = (const float*)d_in[6];
  const float* wv    = (const float*)d_in[7];
  const float* bv    = (const float*)d_in[8];
  const float* wo    = (const float*)d_in[9];
  const float* bo    = (const float*)d_in[10];
  const float* ln2_w = (const float*)d_in[11];
  const float* ln2_b = (const float*)d_in[12];
  const float* w1    = (const float*)d_in[13];
  const float* b1    = (const float*)d_in[14];
  const float* w2    = (const float*)d_in[15];
  const float* b2    = (const float*)d_in[16];
  const float* rel_embed = (const float*)d_in[17];
  const float* gur   = (const float*)d_in[18];
  const float* gi    = (const float*)d_in[19];
  const float* rsc   = (const float*)d_in[20];

  char* ws = (char*)d_ws;
  unsigned short* QKVqk = (unsigned short*)(ws);
  unsigned short* VT    = (unsigned short*)(ws + 12582912);
  unsigned short* Ob    = (unsigned short*)(ws + 18874368);
  float*          X2    = (float*)(ws + 25165824);
  unsigned short* Hb    = (unsigned short*)(ws + 37748736);
  unsigned short* Wqkv  = (unsigned short*)(ws + 44040192);
  unsigned short* Wob   = (unsigned short*)(ws + 47579136);
  unsigned short* W1b   = (unsigned short*)(ws + 48758784);
  unsigned short* W2b   = (unsigned short*)(ws + 53477376);
  float*          bqkv  = (float*)(ws + 58195968);
  float*          bias_rel = (float*)(ws + 58205184);
  float*          qpart = (float*)(ws + 58401744);
  float*          gate  = (float*)(ws + 58409936);
  unsigned short* Fb    = (unsigned short*)(ws);   // FFN hidden aliases [0,25165824)

  // 0. fused weight/bias casts + bias_rel table
  cast_all_kernel<<<3481, 256, 0, stream>>>(wq, wk, wv, wo, w1, w2, bq, bk, bv,
                                            rel_embed, Wqkv, Wob, W1b, W2b,
                                            bias_rel, bqkv);
  // 1. LN1 -> bf16
  ln_kernel<<<Mn, 256, 0, stream>>>(x, ln1_w, ln1_b, Hb);
  // 2. fused QKV projection (N=2304): q|k -> QKVqk (ld 1536), v -> VT transposed
  gemm_mfma_kernel<0, true><<<(QKVS / 128) * (Mn / 128), 256, 0, stream>>>(
      Hb, Wqkv, bqkv, VT, QKVqk, Mn, QKVS, Cn, LQK);
  // 3. gating scalars
  qmean_part_kernel<<<dim3(16, 2), 256, 0, stream>>>(QKVqk, qpart);
  gate_kernel<<<2 * Hn, 64, 0, stream>>>(qpart, gur, gi, rsc, gate);
  // 4. MFMA flash attention
  attn_mfma_kernel<<<dim3(Tn / 64, Hn, 2), 256, 0, stream>>>(QKVqk, VT, bias_rel, gate, Ob);
  // 5. output projection + residual -> fp32 X2 (64x64 tiles, XCD-swizzled)
  gemm_t64_kernel<<<(Cn / 64) * (Mn / 64), 256, 0, stream>>>(
      Ob, Wob, bo, x, X2, Mn, Cn, Cn);
  // 6. LN2 -> bf16
  ln_kernel<<<Mn, 256, 0, stream>>>(X2, ln2_w, ln2_b, Hb);
  // 7. FFN
  gemm_mfma_kernel<2, false><<<(FFn / 128) * (Mn / 128), 256, 0, stream>>>(
      Hb, W1b, b1, nullptr, Fb, Mn, FFn, Cn, FFn);
  gemm_t64_kernel<<<(Cn / 64) * (Mn / 64), 256, 0, stream>>>(
      Fb, W2b, b2, X2, (float*)d_out, Mn, Cn, FFn);
}

// Round 12
// 329.623 us; speedup vs baseline: 1.0390x; 1.0390x over previous
//
#include <hip/hip_runtime.h>
#include <hip/hip_bf16.h>

// TransformerLayer: B=2, T=2048, C=768, H=12, D=64, FF=3072. fp32 I/O.
// Round 12: attention K/V LDS double-buffered with prefetch-after-barrier
// (3 -> 2 barriers/tile, GLDS latency hidden behind QK+softmax; r11 showed
// the kernel is barrier/latency-bound: conflicts were NOT staging-caused);
// t64 GEMM moved to BK=64 split-plane staging (halves barrier count).
//
// Workspace layout (bytes):
//   0         QKVqk bf16 4096x1536 (q|k)      }
//   12582912  VT    bf16 768x4096 (V^T)       } Fb (bf16 4096x3072) aliases
//   18874368  Ob    bf16 4096x768             } [0, 25165824)
//   25165824  X2   fp32 4096x768
//   37748736  Hb   bf16 4096x768 (LN1/LN2 out)
//   44040192  Wqkv bf16 2304x768
//   47579136  Wob  bf16 768x768
//   48758784  W1b  bf16 3072x768
//   53477376  W2b  bf16 768x3072
//   58195968  bqkv fp32 2304
//   58205184  bias_rel fp32 12x4095 (pre-scaled by 1/ln2)
//   58401744  qpart fp32 2x16x64
//   58409936  gate fp32 24

#define Tn 2048
#define Cn 768
#define Hn 12
#define Dn 64
#define FFn 3072
#define Mn 4096
#define QKVS 2304
#define LQK 1536

typedef __attribute__((ext_vector_type(8))) short bfrag;       // 8 bf16 (4 VGPR)
typedef __attribute__((ext_vector_type(8))) unsigned short us8;
typedef __attribute__((ext_vector_type(4))) float f32x4;

#define GLDS(gptr, lptr) __builtin_amdgcn_global_load_lds( \
    (const __attribute__((address_space(1))) void*)(gptr), \
    (__attribute__((address_space(3))) void*)(lptr), 16, 0, 0)

__device__ __forceinline__ unsigned short f2bu(float f){
  __hip_bfloat16 h = __float2bfloat16(f);
  return *(unsigned short*)&h;
}
__device__ __forceinline__ float bu2f(unsigned short u){
  union { unsigned int i; float f; } v; v.i = ((unsigned int)u) << 16; return v.f;
}
__device__ __forceinline__ us8 pack8(float4 a, float4 b){
  us8 c;
  c[0]=f2bu(a.x); c[1]=f2bu(a.y); c[2]=f2bu(a.z); c[3]=f2bu(a.w);
  c[4]=f2bu(b.x); c[5]=f2bu(b.y); c[6]=f2bu(b.z); c[7]=f2bu(b.w);
  return c;
}
__device__ __forceinline__ float fexp2(float x){ return __builtin_amdgcn_exp2f(x); }

__device__ __forceinline__ float block_reduce_sum(float v, float* sred){
  #pragma unroll
  for (int off = 32; off > 0; off >>= 1) v += __shfl_down(v, off, 64);
  __syncthreads();
  if ((threadIdx.x & 63) == 0) sred[threadIdx.x >> 6] = v;
  __syncthreads();
  return sred[0] + sred[1] + sred[2] + sred[3];
}

// ---- fused weight casts + bias_rel table + bias concat ----
// blocks: weights [0,3456) ; bias_rel [3456,3472) ; bqkv [3472,3481)
__global__ __launch_bounds__(256) void cast_all_kernel(
    const float* __restrict__ wq, const float* __restrict__ wk,
    const float* __restrict__ wv, const float* __restrict__ wo,
    const float* __restrict__ w1, const float* __restrict__ w2,
    const float* __restrict__ bq, const float* __restrict__ bk,
    const float* __restrict__ bv, const float* __restrict__ rel_embed,
    unsigned short* __restrict__ Wqkv, unsigned short* __restrict__ Wob,
    unsigned short* __restrict__ W1b, unsigned short* __restrict__ W2b,
    float* __restrict__ bias_rel, float* __restrict__ bqkv)
{
  const int blk = blockIdx.x;
  if (blk >= 3472){
    const int i = (blk - 3472) * 256 + threadIdx.x;   // 0..2303 exactly
    bqkv[i] = (i < Cn) ? bq[i] : (i < 2 * Cn) ? bk[i - Cn] : bv[i - 2 * Cn];
    return;
  }
  if (blk >= 3456){
    const int idx = (blk - 3456) * 256 + threadIdx.x;
    if (idx >= 4095) return;
    const int rel = idx - 2047;
    const int ab = rel < 0 ? -rel : rel;
    int bucket;
    if (ab < 80){
      bucket = ab;
    } else {
      const float lr = logf((float)ab * (1.0f / 80.0f)) * (1.0f / 2.3025851f);
      int lp = 80 + (int)(lr * 80.0f);
      bucket = lp < 159 ? lp : 159;
    }
    if (rel >= 0) bucket += 160;
    #pragma unroll
    for (int h = 0; h < Hn; h++)
      bias_rel[h * 4095 + idx] = rel_embed[bucket * Hn + h] * 1.44269504089f;
    return;
  }
  const float* src; unsigned short* dst; int i;
  if (blk < 288)      { src = wq; dst = Wqkv;               i = blk * 256 + threadIdx.x; }
  else if (blk < 576) { src = wk; dst = Wqkv + Cn * Cn;     i = (blk - 288) * 256 + threadIdx.x; }
  else if (blk < 864) { src = wv; dst = Wqkv + 2 * Cn * Cn; i = (blk - 576) * 256 + threadIdx.x; }
  else if (blk < 1152){ src = wo; dst = Wob;                i = (blk - 864) * 256 + threadIdx.x; }
  else if (blk < 2304){ src = w1; dst = W1b;                i = (blk - 1152) * 256 + threadIdx.x; }
  else                { src = w2; dst = W2b;                i = (blk - 2304) * 256 + threadIdx.x; }
  const float4 a = ((const float4*)src)[i * 2];
  const float4 b = ((const float4*)src)[i * 2 + 1];
  *(us8*)&dst[i * 8] = pack8(a, b);
}

// ---- LayerNorm: fp32 in -> bf16 out ----
__global__ __launch_bounds__(256) void ln_kernel(const float* __restrict__ xin,
    const float* __restrict__ w, const float* __restrict__ bsh,
    unsigned short* __restrict__ out)
{
  __shared__ float xs[Cn];
  __shared__ float sred[4];
  const size_t base = (size_t)blockIdx.x * Cn;
  float s = 0.f;
  for (int c = threadIdx.x; c < Cn; c += 256){
    float v = xin[base + c];
    xs[c] = v; s += v;
  }
  const float mean = block_reduce_sum(s, sred) * (1.f / Cn);
  float s2 = 0.f;
  for (int c = threadIdx.x; c < Cn; c += 256){
    float d = xs[c] - mean; s2 += d * d;
  }
  const float var = block_reduce_sum(s2, sred) * (1.f / Cn);
  const float rstd = rsqrtf(var + 1e-5f);
  for (int c = threadIdx.x; c < Cn; c += 256)
    out[base + c] = f2bu((xs[c] - mean) * rstd * w[c] + bsh[c]);
}

// ---- MFMA GEMM 128x128, single-buffered, XCD-swizzled 1-D grid ----
// id%8 = XCD; each XCD owns 4 consecutive bm-blocks (M=4096 fixed, 32 blocks).
// EPI 0: bf16 out (ldo stride); EPI 2: bf16 out = gelu_exact.
// TRANSV: blocks with bn>=1536 store transposed to vt[col-1536][row] (V^T).
template<int EPI, bool TRANSV>
__global__ __launch_bounds__(256) void gemm_mfma_kernel(
    const unsigned short* __restrict__ A, const unsigned short* __restrict__ Bw,
    const float* __restrict__ bias, unsigned short* __restrict__ vt,
    void* __restrict__ Cout, int M, int N, int K, int ldo)
{
  __shared__ __align__(16) unsigned short As[128 * 32];
  __shared__ __align__(16) unsigned short Bs[128 * 32];
  const int tid = threadIdx.x;
  const int lane = tid & 63, w = tid >> 6;
  const int nl = lane & 15, quad = lane >> 4;
  const int wm = w >> 1, wn = w & 1;
  const int id = blockIdx.x;
  const int bm = ((id & 7) * 4 + ((id >> 3) & 3)) * 128;   // XCD-local bm slice
  const int bn = (id >> 5) * 128;
  const int l4 = lane >> 2, lk = (lane & 3) * 8;

  f32x4 acc[4][4];
  #pragma unroll
  for (int i = 0; i < 4; i++)
    #pragma unroll
    for (int j = 0; j < 4; j++) acc[i][j] = (f32x4){0.f, 0.f, 0.f, 0.f};

  const int c0 = w, c1 = w + 4;
  const unsigned short* A0 = A + (size_t)(bm + c0 * 16 + l4) * K + lk;
  const unsigned short* A1 = A + (size_t)(bm + c1 * 16 + l4) * K + lk;
  const unsigned short* B0 = Bw + (size_t)(bn + c0 * 16 + l4) * K + lk;
  const unsigned short* B1 = Bw + (size_t)(bn + c1 * 16 + l4) * K + lk;

  for (int k0 = 0; k0 < K; k0 += 32){
    __syncthreads();
    GLDS(A0 + k0, &As[c0 * 512]); GLDS(A1 + k0, &As[c1 * 512]);
    GLDS(B0 + k0, &Bs[c0 * 512]); GLDS(B1 + k0, &Bs[c1 * 512]);
    __syncthreads();
    bfrag Af[4], Bf[4];
    #pragma unroll
    for (int mt = 0; mt < 4; mt++)
      Af[mt] = *(const bfrag*)&As[(wm * 64 + mt * 16 + nl) * 32 + quad * 8];
    #pragma unroll
    for (int nt = 0; nt < 4; nt++)
      Bf[nt] = *(const bfrag*)&Bs[(wn * 64 + nt * 16 + nl) * 32 + quad * 8];
    #pragma unroll
    for (int mt = 0; mt < 4; mt++)
      #pragma unroll
      for (int nt = 0; nt < 4; nt++)
        acc[mt][nt] = __builtin_amdgcn_mfma_f32_16x16x32_bf16(Af[mt], Bf[nt], acc[mt][nt], 0, 0, 0);
  }

  if (TRANSV && bn >= 1536){
    #pragma unroll
    for (int nt = 0; nt < 4; nt++){
      const int col = bn + wn * 64 + nt * 16 + nl;
      const float bv_ = bias[col];
      const int vcol = col - 1536;
      #pragma unroll
      for (int mt = 0; mt < 4; mt++){
        const int row0 = bm + wm * 64 + mt * 16 + quad * 4;
        unsigned short pk[4];
        #pragma unroll
        for (int r = 0; r < 4; r++) pk[r] = f2bu(acc[mt][nt][r] + bv_);
        *(uint2*)&vt[(size_t)vcol * Mn + row0] = *(uint2*)pk;
      }
    }
    return;
  }
  #pragma unroll
  for (int nt = 0; nt < 4; nt++){
    const int col = bn + wn * 64 + nt * 16 + nl;
    const float bv_ = bias[col];
    #pragma unroll
    for (int mt = 0; mt < 4; mt++){
      const int row0 = bm + wm * 64 + mt * 16 + quad * 4;
      #pragma unroll
      for (int r = 0; r < 4; r++){
        const size_t idx = (size_t)(row0 + r) * ldo + col;
        const float v = acc[mt][nt][r] + bv_;
        if (EPI == 2){
          ((unsigned short*)Cout)[idx] = f2bu(0.5f * v * (1.f + erff(v * 0.70710678118f)));
        } else {
          ((unsigned short*)Cout)[idx] = f2bu(v);
        }
      }
    }
  }
}

// ---- MFMA GEMM 64x64 tiles, BK=64 split-plane, XCD-swizzled 1-D grid ----
// fp32 out = acc+bias+res. id%8 = XCD; XCD owns 8 consecutive bm-blocks.
__global__ __launch_bounds__(256) void gemm_t64_kernel(
    const unsigned short* __restrict__ A, const unsigned short* __restrict__ Bw,
    const float* __restrict__ bias, const float* __restrict__ res,
    float* __restrict__ Cout, int M, int N, int K)
{
  __shared__ __align__(16) unsigned short As[2 * 64 * 32];  // [plane][row][32]
  __shared__ __align__(16) unsigned short Bs[2 * 64 * 32];
  const int tid = threadIdx.x;
  const int lane = tid & 63, w = tid >> 6;
  const int nl = lane & 15, quad = lane >> 4;
  const int id = blockIdx.x;
  const int bm = ((id & 7) * 8 + ((id >> 3) & 7)) * 64;    // XCD-local bm slice
  const int bn = (id >> 6) * 64;
  const int l2 = lane >> 2, l3 = (lane & 3) * 8;

  f32x4 acc[4];
  #pragma unroll
  for (int j = 0; j < 4; j++) acc[j] = (f32x4){0.f, 0.f, 0.f, 0.f};

  const unsigned short* A0 = A + (size_t)(bm + w * 16 + l2) * K + l3;
  const unsigned short* B0 = Bw + (size_t)(bn + w * 16 + l2) * K + l3;

  for (int k0 = 0; k0 < K; k0 += 64){
    __syncthreads();
    GLDS(A0 + k0,      &As[w * 512]);
    GLDS(A0 + k0 + 32, &As[2048 + w * 512]);
    GLDS(B0 + k0,      &Bs[w * 512]);
    GLDS(B0 + k0 + 32, &Bs[2048 + w * 512]);
    __syncthreads();
    const bfrag Af0 = *(const bfrag*)&As[(w * 16 + nl) * 32 + quad * 8];
    const bfrag Af1 = *(const bfrag*)&As[2048 + (w * 16 + nl) * 32 + quad * 8];
    bfrag Bf0[4], Bf1[4];
    #pragma unroll
    for (int nt = 0; nt < 4; nt++){
      Bf0[nt] = *(const bfrag*)&Bs[(nt * 16 + nl) * 32 + quad * 8];
      Bf1[nt] = *(const bfrag*)&Bs[2048 + (nt * 16 + nl) * 32 + quad * 8];
    }
    #pragma unroll
    for (int nt = 0; nt < 4; nt++){
      acc[nt] = __builtin_amdgcn_mfma_f32_16x16x32_bf16(Af0, Bf0[nt], acc[nt], 0, 0, 0);
      acc[nt] = __builtin_amdgcn_mfma_f32_16x16x32_bf16(Af1, Bf1[nt], acc[nt], 0, 0, 0);
    }
  }

  const int row0 = bm + w * 16 + quad * 4;
  #pragma unroll
  for (int nt = 0; nt < 4; nt++){
    const int col = bn + nt * 16 + nl;
    const float bv_ = bias[col];
    #pragma unroll
    for (int r = 0; r < 4; r++){
      const size_t idx = (size_t)(row0 + r) * N + col;
      Cout[idx] = acc[nt][r] + bv_ + res[idx];
    }
  }
}

// ---- qmean stage 1 (Q cols of QKVqk, stride 1536) ----
__global__ __launch_bounds__(256) void qmean_part_kernel(
    const unsigned short* __restrict__ QKVqk, float* __restrict__ qpart)
{
  __shared__ float ps[Cn];
  const int b = blockIdx.y, t0 = blockIdx.x * 128;
  const int tid = threadIdx.x;
  float a0 = 0.f, a1 = 0.f, a2 = 0.f;
  for (int r = 0; r < 128; r++){
    const size_t base = (size_t)(b * Tn + t0 + r) * LQK;
    a0 += bu2f(QKVqk[base + tid]);
    a1 += bu2f(QKVqk[base + tid + 256]);
    a2 += bu2f(QKVqk[base + tid + 512]);
  }
  ps[tid] = a0; ps[tid + 256] = a1; ps[tid + 512] = a2;
  __syncthreads();
  if (tid < Dn){
    float s = 0.f;
    #pragma unroll
    for (int hh = 0; hh < Hn; hh++) s += ps[hh * Dn + tid];
    qpart[(b * 16 + blockIdx.x) * Dn + tid] = s;
  }
}

// ---- gate[b,h] ----
__global__ __launch_bounds__(64) void gate_kernel(const float* __restrict__ qpart,
    const float* __restrict__ gur, const float* __restrict__ gi,
    const float* __restrict__ rsc, float* __restrict__ gate)
{
  const int b = blockIdx.x / Hn, h = blockIdx.x % Hn;
  const int d = threadIdx.x;
  float s = 0.f;
  #pragma unroll
  for (int blk = 0; blk < 16; blk++) s += qpart[(b * 16 + blk) * Dn + d];
  const float g = s * (1.f / (Hn * Tn));
  float vr = g * gur[h * Dn + d];
  float vu = g * gi[h * Dn + d];
  #pragma unroll
  for (int off = 32; off > 0; off >>= 1){
    vr += __shfl_down(vr, off, 64);
    vu += __shfl_down(vu, off, 64);
  }
  if (d == 0){
    const float gr = 1.f / (1.f + __expf(-vr));
    const float gu = 1.f / (1.f + __expf(-vu));
    gate[blockIdx.x] = 1.f + gu * rsc[h] * gr;
  }
}

// ---- MFMA flash attention; K/V double-buffered GLDS, prefetch overlap ----
// LDS: Qs 64x72 (dies -> bias_blk) | KsP [2bufs][2planes][64][32] |
//      VtP [2][2][64][32] | Ptq 64x72 | lsh 4x64.  Total 52224 B.
// Loop: barrier (tile-t ready, buf nxt free) -> GLDS t+1 into nxt ->
//       QK+softmax from cur (hides load latency) -> barrier (Ptq) -> PV.
__global__ __launch_bounds__(256) void attn_mfma_kernel(
    const unsigned short* __restrict__ QKVqk, const unsigned short* __restrict__ VT,
    const float* __restrict__ bias_rel, const float* __restrict__ gate,
    unsigned short* __restrict__ O)
{
  __shared__ __align__(16) char smem[52224];
  unsigned short* Qs = (unsigned short*)smem;            // 64x72, dies -> bias
  float* bias_blk    = (float*)smem;                     // 2111 floats
  unsigned short* KsP = (unsigned short*)(smem + 9216);  // [2][2][64][32]
  unsigned short* VtP = (unsigned short*)(smem + 25600); // [2][2][64][32]
  unsigned short* Ptq = (unsigned short*)(smem + 41984); // [query][key] 64x72
  float* lsh         = (float*)(smem + 51200);           // [wave][query] 4x64

  const int qbase = blockIdx.x * 64;
  const int h = blockIdx.y, b = blockIdx.z;
  const int tid = threadIdx.x;
  const float g = gate[b * Hn + h];
  const float* brow = bias_rel + h * 4095 + 1984 - qbase;
  const unsigned short* Q = QKVqk;
  const unsigned short* K = QKVqk + Cn;

  const int lane = tid & 63, w = tid >> 6;
  const int nl = lane & 15, quad = lane >> 4;
  const int l2 = lane >> 2, l3 = (lane & 3) * 8;

  // GLDS staging pointers: wave w stages K-keys/V-dims [w*16, w*16+16)
  const unsigned short* kg0 = K + (size_t)(b * Tn + w * 16 + l2) * LQK + h * Dn + l3;
  const unsigned short* vg0 = VT + (size_t)(h * Dn + w * 16 + l2) * Mn + (size_t)b * Tn + l3;

  // preload tile 0 into buffer 0 (drained by the first barrier below)
  GLDS(kg0,      KsP + w * 512);
  GLDS(kg0 + 32, KsP + 2048 + w * 512);
  GLDS(vg0,      VtP + w * 512);
  GLDS(vg0 + 32, VtP + 2048 + w * 512);

  // stage Q [query][dim]
  {
    const int row = tid >> 2, cg = (tid & 3) * 16;
    const us8* qp = (const us8*)(Q + (size_t)(b * Tn + qbase + row) * LQK + h * Dn + cg);
    *(us8*)&Qs[row * 72 + cg]     = qp[0];
    *(us8*)&Qs[row * 72 + cg + 8] = qp[1];
  }
  __syncthreads();

  bfrag Qb[4][2];
  #pragma unroll
  for (int mt = 0; mt < 4; mt++){
    Qb[mt][0] = *(const bfrag*)&Qs[(mt * 16 + nl) * 72 + quad * 8];
    Qb[mt][1] = *(const bfrag*)&Qs[(mt * 16 + nl) * 72 + 32 + quad * 8];
  }
  __syncthreads();           // everyone done reading Qs
  for (int j = tid; j < 2111; j += 256) bias_blk[j] = brow[j] * g;

  const int wq = w & 1, wd = w >> 1;
  f32x4 Oa[2][2];            // [query-half a][dim-half d0]
  #pragma unroll
  for (int a = 0; a < 2; a++)
    #pragma unroll
    for (int d0 = 0; d0 < 2; d0++) Oa[a][d0] = (f32x4){0.f, 0.f, 0.f, 0.f};
  float l_part[4] = {0.f, 0.f, 0.f, 0.f};

  for (int kt = 0; kt < 32; kt++){
    const int kbase = kt * 64;
    const int cur = (kt & 1) * 4096;      // element offset of current buffer
    const int nxt = 4096 - cur;
    __syncthreads();                      // tile-t data ready; buf nxt free
    if (kt < 31){                         // prefetch t+1 (in flight during QK)
      const unsigned short* kg = kg0 + (size_t)(kbase + 64) * LQK;
      const unsigned short* vg = vg0 + kbase + 64;
      GLDS(kg,      KsP + nxt + w * 512);
      GLDS(kg + 32, KsP + nxt + 2048 + w * 512);
      GLDS(vg,      VtP + nxt + w * 512);
      GLDS(vg + 32, VtP + nxt + 2048 + w * 512);
    }

    // S^T: wave w owns key-subtile w. A = K frags (plane-split).
    const bfrag Ka0 = *(const bfrag*)&KsP[cur + (w * 16 + nl) * 32 + quad * 8];
    const bfrag Ka1 = *(const bfrag*)&KsP[cur + 2048 + (w * 16 + nl) * 32 + quad * 8];
    const int bofs = kbase + w * 16 + quad * 4 + 63 - nl;
    #pragma unroll
    for (int mt = 0; mt < 4; mt++){
      f32x4 z = (f32x4){0.f, 0.f, 0.f, 0.f};
      z = __builtin_amdgcn_mfma_f32_16x16x32_bf16(Ka0, Qb[mt][0], z, 0, 0, 0);
      z = __builtin_amdgcn_mfma_f32_16x16x32_bf16(Ka1, Qb[mt][1], z, 0, 0, 0);
      unsigned short pk[4];
      #pragma unroll
      for (int r = 0; r < 4; r++){
        const float p = fexp2(z[r] * 0.18033688f + bias_blk[bofs - mt * 16 + r]);
        l_part[mt] += p;
        pk[r] = f2bu(p);
      }
      *(uint2*)&Ptq[(mt * 16 + nl) * 72 + w * 16 + quad * 4] = *(uint2*)pk;
    }
    __syncthreads();                    // P visible (drains prefetch post-QK)

    // O^T += V^T.P : wave (wq, wd): queries wq*32..+31, dims wd*32..+31
    bfrag Vf[2][2], Pf[2][2];
    #pragma unroll
    for (int d0 = 0; d0 < 2; d0++){
      const int dt = wd * 2 + d0;
      Vf[d0][0] = *(const bfrag*)&VtP[cur + (dt * 16 + nl) * 32 + quad * 8];
      Vf[d0][1] = *(const bfrag*)&VtP[cur + 2048 + (dt * 16 + nl) * 32 + quad * 8];
    }
    #pragma unroll
    for (int a = 0; a < 2; a++){
      const int qt = wq * 2 + a;
      Pf[a][0] = *(const bfrag*)&Ptq[(qt * 16 + nl) * 72 + quad * 8];
      Pf[a][1] = *(const bfrag*)&Ptq[(qt * 16 + nl) * 72 + 32 + quad * 8];
    }
    #pragma unroll
    for (int a = 0; a < 2; a++)
      #pragma unroll
      for (int d0 = 0; d0 < 2; d0++){
        Oa[a][d0] = __builtin_amdgcn_mfma_f32_16x16x32_bf16(Vf[d0][0], Pf[a][0], Oa[a][d0], 0, 0, 0);
        Oa[a][d0] = __builtin_amdgcn_mfma_f32_16x16x32_bf16(Vf[d0][1], Pf[a][1], Oa[a][d0], 0, 0, 0);
      }
  }

  // ---- epilogue ----
  #pragma unroll
  for (int mt = 0; mt < 4; mt++){
    float l = l_part[mt];
    l += __shfl_xor(l, 16, 64);
    l += __shfl_xor(l, 32, 64);
    if (quad == 0) lsh[w * 64 + mt * 16 + nl] = l;
  }
  __syncthreads();
  #pragma unroll
  for (int a = 0; a < 2; a++){
    const int q = (wq * 2 + a) * 16 + nl;
    const float linv = 1.f / (lsh[q] + lsh[64 + q] + lsh[128 + q] + lsh[192 + q]);
    unsigned short* orow = O + (size_t)(b * Tn + qbase + q) * Cn + h * Dn;
    #pragma unroll
    for (int d0 = 0; d0 < 2; d0++){
      unsigned short pk[4];
      #pragma unroll
      for (int r = 0; r < 4; r++) pk[r] = f2bu(Oa[a][d0][r] * linv);
      *(uint2*)&orow[(wd * 2 + d0) * 16 + quad * 4] = *(uint2*)pk;
    }
  }
}

extern "C" void kernel_launch(void* const* d_in, const int* in_sizes, int n_in,
                              void* d_out, int out_size, void* d_ws, size_t ws_size,
                              hipStream_t stream)
{
  const float* x     = (const float*)d_in[0];
  const float* ln1_w = (const float*)d_in[1];
  const float* ln1_b = (const float*)d_in[2];
  const float* wq    = (const float*)d_in[3];
  const float* bq    = (const float*)d_in[4];
  const float* wk    = (const float*)d_in[5];
  const float* bk    = (const float*)d_in[6];
  const float* wv    = (const float*)d_in[7];
  const float* bv    = (const float*)d_in[8];
  const float* wo    = (const float*)d_in[9];
  const float* bo    = (const float*)d_in[10];
  const float* ln2_w = (const float*)d_in[11];
  const float* ln2_b = (const float*)d_in[12];
  const float* w1    = (const float*)d_in[13];
  const float* b1    = (const float*)d_in[14];
  const float* w2    = (const float*)d_in[15];
  const float* b2    = (const float*)d_in[16];
  const float* rel_embed = (const float*)d_in[17];
  const float* gur   = (const float*)d_in[18];
  const float* gi    = (const float*)d_in[19];
  const float* rsc   = (const float*)d_in[20];

  char* ws = (char*)d_ws;
  unsigned short* QKVqk = (unsigned short*)(ws);
  unsigned short* VT    = (unsigned short*)(ws + 12582912);
  unsigned short* Ob    = (unsigned short*)(ws + 18874368);
  float*          X2    = (float*)(ws + 25165824);
  unsigned short* Hb    = (unsigned short*)(ws + 37748736);
  unsigned short* Wqkv  = (unsigned short*)(ws + 44040192);
  unsigned short* Wob   = (unsigned short*)(ws + 47579136);
  unsigned short* W1b   = (unsigned short*)(ws + 48758784);
  unsigned short* W2b   = (unsigned short*)(ws + 53477376);
  float*          bqkv  = (float*)(ws + 58195968);
  float*          bias_rel = (float*)(ws + 58205184);
  float*          qpart = (float*)(ws + 58401744);
  float*          gate  = (float*)(ws + 58409936);
  unsigned short* Fb    = (unsigned short*)(ws);   // FFN hidden aliases [0,25165824)

  // 0. fused weight/bias casts + bias_rel table
  cast_all_kernel<<<3481, 256, 0, stream>>>(wq, wk, wv, wo, w1, w2, bq, bk, bv,
                                            rel_embed, Wqkv, Wob, W1b, W2b,
                                            bias_rel, bqkv);
  // 1. LN1 -> bf16
  ln_kernel<<<Mn, 256, 0, stream>>>(x, ln1_w, ln1_b, Hb);
  // 2. fused QKV projection (N=2304): q|k -> QKVqk (ld 1536), v -> VT transposed
  gemm_mfma_kernel<0, true><<<(QKVS / 128) * (Mn / 128), 256, 0, stream>>>(
      Hb, Wqkv, bqkv, VT, QKVqk, Mn, QKVS, Cn, LQK);
  // 3. gating scalars
  qmean_part_kernel<<<dim3(16, 2), 256, 0, stream>>>(QKVqk, qpart);
  gate_kernel<<<2 * Hn, 64, 0, stream>>>(qpart, gur, gi, rsc, gate);
  // 4. MFMA flash attention
  attn_mfma_kernel<<<dim3(Tn / 64, Hn, 2), 256, 0, stream>>>(QKVqk, VT, bias_rel, gate, Ob);
  // 5. output projection + residual -> fp32 X2 (64x64 tiles, XCD-swizzled)
  gemm_t64_kernel<<<(Cn / 64) * (Mn / 64), 256, 0, stream>>>(
      Ob, Wob, bo, x, X2, Mn, Cn, Cn);
  // 6. LN2 -> bf16
  ln_kernel<<<Mn, 256, 0, stream>>>(X2, ln2_w, ln2_b, Hb);
  // 7. FFN
  gemm_mfma_kernel<2, false><<<(FFn / 128) * (Mn / 128), 256, 0, stream>>>(
      Hb, W1b, b1, nullptr, Fb, Mn, FFn, Cn, FFn);
  gemm_t64_kernel<<<(Cn / 64) * (Mn / 64), 256, 0, stream>>>(
      Fb, W2b, b2, X2, (float*)d_out, Mn, Cn, FFn);
}